// Round 3
// baseline (421.409 us; speedup 1.0000x reference)
//
#include <hip/hip_runtime.h>
#include <hip/hip_bf16.h>

#define NFFT 8192
#define TPB  512
#define VPT  16   // NFFT / TPB
#define ROWS 4    // rows per block: 2048/4 = 512 blocks = exactly 2 resident/CU

// Native 2-wide float vector => compiler emits v_pk_add_f32 / v_pk_fma_f32.
typedef float f2 __attribute__((ext_vector_type(2)));

__device__ __forceinline__ f2 mk(float a, float b){ f2 r; r.x=a; r.y=b; return r; }
__device__ __forceinline__ f2 cswap(f2 a){ return __builtin_shufflevector(a,a,1,0); }

// Raw barrier: lgkmcnt(0)+s_barrier in ONE opaque asm. Unlike __syncthreads()
// this does NOT drain vmcnt, so prefetch global_loads and output stores stay in
// flight across barriers. Correctness proven in R1/R2 (passed, absmax 0).
// The memory clobber also pins global loads issued before it: the compiler
// cannot rematerialize (re-load) prefetched values across it.
__device__ __forceinline__ void bar_lds() {
  asm volatile("s_waitcnt lgkmcnt(0)\n\ts_barrier" ::: "memory");
}

// XOR swizzle at f2 granularity (physical layout identical to R4/R5).
// Rounds below use closed-form identities so swz costs 0-2 VALU per access:
//   swz(p + 1024k) = swz(p) + 1024k
//   swz(b + 128k)  = (swz(b) ^ 8(k&1)) + 128k
//   swz(b + 16k)   = (b&~15) + 16k + ((b&15) ^ 8(blk&1) ^ k)
//   swz(16t + c)   = 16t + (c ^ (t&15))
__device__ __forceinline__ int swz(int j) { return j ^ ((j >> 4) & 15); }
__device__ __forceinline__ int rev13(unsigned x) { return (int)(__brev(x) >> 19); }

// d * (c - i s)  (forward twiddle)
__device__ __forceinline__ f2 cmul_conj(f2 d, float c, float s){
  return d*c + cswap(d)*mk(s,-s);
}
// v * (c + i s)  (inverse twiddle)
__device__ __forceinline__ f2 cmul_pos(f2 v, float c, float s){
  return v*c + cswap(v)*mk(-s,s);
}

// ---- radix-8 butterfly cores; hw sin/cos in revolutions (verified R2-R5) ----
__device__ __forceinline__ void dif8_core(f2* y, int p_num, float inv_den) {
  float cA[4], sA[4], cB[2], sB[2], c4, s4;
  {
    float r = (float)p_num * inv_den;
    float sa = __builtin_amdgcn_sinf(r);
    float ca = __builtin_amdgcn_cosf(r);
    float c2 = ca*ca - sa*sa, s2 = 2.0f*ca*sa;
    c4 = c2*c2 - s2*s2; s4 = 2.0f*c2*s2;
    const float R = 0.70710678118654752f;
    cA[0] = ca;          sA[0] = sa;
    cA[1] = R*(ca-sa);   sA[1] = R*(ca+sa);
    cA[2] = -sa;         sA[2] = ca;
    cA[3] = -R*(ca+sa);  sA[3] = R*(ca-sa);
    cB[0] = c2;  sB[0] = s2;
    cB[1] = -s2; sB[1] = c2;
  }
  #pragma unroll
  for (int k = 0; k < 4; ++k) {
    f2 u = y[k], v = y[k+4];
    y[k] = u + v;
    y[k+4] = cmul_conj(u - v, cA[k], sA[k]);
  }
  #pragma unroll
  for (int h = 0; h < 8; h += 4)
    #pragma unroll
    for (int k0 = 0; k0 < 2; ++k0) {
      f2 u = y[h+k0], v = y[h+k0+2];
      y[h+k0] = u + v;
      y[h+k0+2] = cmul_conj(u - v, cB[k0], sB[k0]);
    }
  #pragma unroll
  for (int h = 0; h < 8; h += 2) {
    f2 u = y[h], v = y[h+1];
    y[h] = u + v;
    y[h+1] = cmul_conj(u - v, c4, s4);
  }
}

__device__ __forceinline__ void dit8_core(f2* y, int p_num, float inv_den) {
  float cA[4], sA[4], cB[2], sB[2], c4, s4;
  {
    float r = (float)p_num * inv_den;
    float sa = __builtin_amdgcn_sinf(r);
    float ca = __builtin_amdgcn_cosf(r);
    float c2 = ca*ca - sa*sa, s2 = 2.0f*ca*sa;
    c4 = c2*c2 - s2*s2; s4 = 2.0f*c2*s2;
    const float R = 0.70710678118654752f;
    cA[0] = ca;          sA[0] = sa;
    cA[1] = R*(ca-sa);   sA[1] = R*(ca+sa);
    cA[2] = -sa;         sA[2] = ca;
    cA[3] = -R*(ca+sa);  sA[3] = R*(ca-sa);
    cB[0] = c2;  sB[0] = s2;
    cB[1] = -s2; sB[1] = c2;
  }
  #pragma unroll
  for (int h = 0; h < 8; h += 2) {
    f2 u = y[h];
    f2 w = cmul_pos(y[h+1], c4, s4);
    y[h] = u + w; y[h+1] = u - w;
  }
  #pragma unroll
  for (int h = 0; h < 8; h += 4)
    #pragma unroll
    for (int k0 = 0; k0 < 2; ++k0) {
      f2 u = y[h+k0];
      f2 w = cmul_pos(y[h+k0+2], cB[k0], sB[k0]);
      y[h+k0] = u + w; y[h+k0+2] = u - w;
    }
  #pragma unroll
  for (int k = 0; k < 4; ++k) {
    f2 u = y[k];
    f2 w = cmul_pos(y[k+4], cA[k], sA[k]);
    y[k] = u + w; y[k+4] = u - w;
  }
}

// ---- GLOBAL forward round S=1024: swz(p+1024k) = swz(p)+1024k -> imm offsets
__device__ __forceinline__ void dif_global1024(f2* z, int t) {
  #pragma unroll
  for (int gi = 0; gi < 2; ++gi) {
    int p = t + TPB*gi;
    f2* B = z + swz(p);
    f2 y[8];
    #pragma unroll
    for (int k = 0; k < 8; ++k) y[k] = B[1024*k];
    dif8_core(y, p, 0.125f/1024.0f);
    #pragma unroll
    for (int k = 0; k < 8; ++k) B[1024*k] = y[k];
  }
  bar_lds();
}

// ---- WAVE-LOCAL S=128: two bases (swz(b), swz(b)^8) + imm offsets.
// No fence: a wave's DS ops retire in order (lgkmcnt in-order for LDS),
// so own-wave read-after-write across rounds is safe and pipelines.
__device__ __forceinline__ void dif_wave128(f2* z, int w, int l) {
  #pragma unroll
  for (int gi = 0; gi < 2; ++gi) {
    int gl = l + 64*gi;
    int E = swz(w*1024 + gl);
    f2* B0 = z + E;
    f2* B1 = z + (E ^ 8);
    f2 y[8];
    #pragma unroll
    for (int k = 0; k < 8; ++k) y[k] = (k&1) ? B1[128*k] : B0[128*k];
    dif8_core(y, gl, 0.125f/128.0f);
    #pragma unroll
    for (int k = 0; k < 8; ++k) { if (k&1) B1[128*k] = y[k]; else B0[128*k] = y[k]; }
  }
}

__device__ __forceinline__ void dit_wave128(f2* z, int w, int l) {
  #pragma unroll
  for (int gi = 0; gi < 2; ++gi) {
    int gl = l + 64*gi;
    int E = swz(w*1024 + gl);
    f2* B0 = z + E;
    f2* B1 = z + (E ^ 8);
    f2 y[8];
    #pragma unroll
    for (int k = 0; k < 8; ++k) y[k] = (k&1) ? B1[128*k] : B0[128*k];
    dit8_core(y, gl, 0.125f/128.0f);
    #pragma unroll
    for (int k = 0; k < 8; ++k) { if (k&1) B1[128*k] = y[k]; else B0[128*k] = y[k]; }
  }
}

// ---- WAVE-LOCAL S=16: swz(b+16k) = H + 16k + (e^k), e = p ^ 8(blk&1)
__device__ __forceinline__ void dif_wave16(f2* z, int w, int l) {
  #pragma unroll
  for (int gi = 0; gi < 2; ++gi) {
    int gl = l + 64*gi;
    int p = gl & 15, blk = gl >> 4;
    int e = p ^ (8*(blk&1));
    f2* H = z + (w*1024 + blk*128);
    f2 y[8];
    #pragma unroll
    for (int k = 0; k < 8; ++k) y[k] = H[16*k + (e ^ k)];
    dif8_core(y, p, 0.125f/16.0f);
    #pragma unroll
    for (int k = 0; k < 8; ++k) H[16*k + (e ^ k)] = y[k];
  }
}

__device__ __forceinline__ void dit_wave16(f2* z, int w, int l) {
  #pragma unroll
  for (int gi = 0; gi < 2; ++gi) {
    int gl = l + 64*gi;
    int p = gl & 15, blk = gl >> 4;
    int e = p ^ (8*(blk&1));
    f2* H = z + (w*1024 + blk*128);
    f2 y[8];
    #pragma unroll
    for (int k = 0; k < 8; ++k) y[k] = H[16*k + (e ^ k)];
    dit8_core(y, p, 0.125f/16.0f);
    #pragma unroll
    for (int k = 0; k < 8; ++k) H[16*k + (e ^ k)] = y[k];
  }
}

#define C16_1 0.92387953251128674f
#define S16_1 0.38268343236508978f
#define RSQ2  0.70710678118654752f

// ---- radix-16 const-twiddle rounds: swz(16t+c) = 16t + (c ^ (t&15))
__device__ __forceinline__ void dif16_x(f2* z, int t) {
  const float C8[8] = {1.f, C16_1, RSQ2, S16_1, 0.f, -S16_1, -RSQ2, -C16_1};
  const float S8[8] = {0.f, S16_1, RSQ2, C16_1, 1.f,  C16_1,  RSQ2,  S16_1};
  int e = t & 15;
  f2* H = z + 16*t;
  f2 y[16];
  #pragma unroll
  for (int c = 0; c < 16; ++c) y[c] = H[c ^ e];
  #pragma unroll
  for (int j = 0; j < 8; ++j) {
    f2 u = y[j], v = y[j+8];
    y[j] = u + v;
    y[j+8] = cmul_conj(u - v, C8[j], S8[j]);
  }
  #pragma unroll
  for (int h = 0; h < 16; h += 8)
    #pragma unroll
    for (int j = 0; j < 4; ++j) {
      f2 u = y[h+j], v = y[h+j+4];
      y[h+j] = u + v;
      y[h+j+4] = cmul_conj(u - v, C8[2*j], S8[2*j]);
    }
  #pragma unroll
  for (int h = 0; h < 16; h += 4)
    #pragma unroll
    for (int j = 0; j < 2; ++j) {
      f2 u = y[h+j], v = y[h+j+2];
      y[h+j] = u + v;
      f2 d = u - v;
      y[h+j+2] = j ? mk(d.y, -d.x) : d;
    }
  #pragma unroll
  for (int h = 0; h < 16; h += 2) {
    f2 u = y[h], v = y[h+1];
    y[h] = u + v; y[h+1] = u - v;
  }
  #pragma unroll
  for (int c = 0; c < 16; ++c) H[c ^ e] = y[c];
}

__device__ __forceinline__ void dit16_x(f2* z, int t) {
  const float C8[8] = {1.f, C16_1, RSQ2, S16_1, 0.f, -S16_1, -RSQ2, -C16_1};
  const float S8[8] = {0.f, S16_1, RSQ2, C16_1, 1.f,  C16_1,  RSQ2,  S16_1};
  int e = t & 15;
  f2* H = z + 16*t;
  f2 y[16];
  #pragma unroll
  for (int c = 0; c < 16; ++c) y[c] = H[c ^ e];
  #pragma unroll
  for (int h = 0; h < 16; h += 2) {
    f2 u = y[h], v = y[h+1];
    y[h] = u + v; y[h+1] = u - v;
  }
  #pragma unroll
  for (int h = 0; h < 16; h += 4)
    #pragma unroll
    for (int j = 0; j < 2; ++j) {
      f2 u = y[h+j];
      f2 v = y[h+j+2];
      f2 w = j ? mk(-v.y, v.x) : v;
      y[h+j] = u + w; y[h+j+2] = u - w;
    }
  #pragma unroll
  for (int h = 0; h < 16; h += 8)
    #pragma unroll
    for (int j = 0; j < 4; ++j) {
      f2 u = y[h+j];
      f2 w = cmul_pos(y[h+j+4], C8[2*j], S8[2*j]);
      y[h+j] = u + w; y[h+j+4] = u - w;
    }
  #pragma unroll
  for (int j = 0; j < 8; ++j) {
    f2 u = y[j];
    f2 w = cmul_pos(y[j+8], C8[j], S8[j]);
    y[j] = u + w; y[j+8] = u - w;
  }
  #pragma unroll
  for (int c = 0; c < 16; ++c) H[c ^ e] = y[c];
}

// Last inverse round (global S=1024): imm offsets; results stay in registers.
__device__ __forceinline__ void dit_last(const f2* z, int t, float* re, float& mv) {
  #pragma unroll
  for (int gi = 0; gi < 2; ++gi) {
    int g = t + TPB*gi;
    const f2* B = z + swz(g);
    f2 y[8];
    #pragma unroll
    for (int k = 0; k < 8; ++k) y[k] = B[1024*k];
    dit8_core(y, g, 0.125f/1024.0f);
    #pragma unroll
    for (int k = 0; k < 8; ++k) {
      re[8*gi + k] = y[k].x;     // corr*N at position g + 1024*k
      mv = fmaxf(mv, y[k].x);
    }
  }
}

// NO waves-per-EU constraint (R2/Round-1: min-occupancy bound => 64-VGPR target
// => ~1.1 GB spill). Plain bound gave VGPR=80 spill-free in Round-0.
// Prefetch live range is now ONLY argmax->next staging (low-pressure phase),
// so peak stays at the FFT's ~80, not 80+32.
__global__ __launch_bounds__(TPB)
void corr_align_kernel(const float* __restrict__ x, const float* __restrict__ xref,
                       float* __restrict__ out0, float* __restrict__ outInd,
                       int nrows) {
  __shared__ f2 z[NFFT];   // 64 KiB
  const int t = threadIdx.x;
  const int lane = t & 63, wave = t >> 6;
  const int row0 = blockIdx.x * ROWS;
  const int rmax = (nrows - row0 < ROWS) ? (nrows - row0) : ROWS;

  // ---- prefetch row0 inputs into registers (8x dwordx4 = 32 VGPRs).
  //      Row 0 has nothing to hide under; rows 1..3 prefetch late (below).
  float4 sx[4], sr[4];
  {
    const float4* x4 = (const float4*)(x + (size_t)row0 * NFFT);
    const float4* r4 = (const float4*)(xref + (size_t)row0 * NFFT);
    #pragma unroll
    for (int gi = 0; gi < 4; ++gi) { int q = t + TPB*gi; sx[gi] = x4[q]; sr[gi] = r4[q]; }
  }

  for (int r = 0; r < rmax; ++r) {
    const int row = row0 + r;
    const float* xrow = x + (size_t)row * NFFT;
    const float* rrow = xref + (size_t)row * NFFT;

    // z was argmax scratch for the previous row: all readers must be done.
    bar_lds();

    // ---- stage: z[n] = x[n] + i*xref[n] (from prefetched regs) ----
    // NOTE: no float4 LDS stores possible: swz(4q) can be odd (misaligned).
    #pragma unroll
    for (int gi = 0; gi < 4; ++gi) {
      int q = t + TPB*gi;
      float4 xv = sx[gi], rv = sr[gi];
      int j = 4*q;
      z[swz(j+0)] = mk(xv.x, rv.x);
      z[swz(j+1)] = mk(xv.y, rv.y);
      z[swz(j+2)] = mk(xv.z, rv.z);
      z[swz(j+3)] = mk(xv.w, rv.w);
    }
    bar_lds();
    // sx/sr are DEAD here: ds_write consumed them at issue. They are re-defined
    // only after dit_last (low register pressure region), so the FFT below runs
    // at Round-0's ~80-VGPR peak, not 80+32.

    // ---- forward DIF FFT: natural -> bit-reversed ----
    dif_global1024(z, t);          // cross-wave, bar_lds inside
    dif_wave128(z, wave, lane);    // wave-local: own-chunk, DS-order safe
    dif_wave16(z, wave, lane);
    dif16_x(z, t);
    bar_lds();                     // unpack reads cross-chunk

    // ---- unpack + cross-spectrum, PAIR-OWNED ----
    #pragma unroll
    for (int gi = 0; gi < 8; ++gi) {
      int k = 8*t + gi + 1;                       // 1..4096
      int p = rev13((unsigned)k);
      int q = rev13((unsigned)((NFFT - k) & (NFFT-1)));
      f2 Zp = z[swz(p)];
      f2 Zq = z[swz(q)];
      float Xx = 0.5f*(Zp.x + Zq.x);
      float Xy = 0.5f*(Zp.y - Zq.y);
      float Yx = 0.5f*(Zp.y + Zq.y);
      float Yy = 0.5f*(Zq.x - Zp.x);
      f2 Gk = mk(Xx*Yx + Xy*Yy, Xx*Yy - Xy*Yx);
      z[swz(p)] = Gk;
      if (k != NFFT/2) z[swz(q)] = mk(Gk.x, -Gk.y);
    }
    if (t == 0) {
      f2 Z0 = z[0];
      z[0] = mk(Z0.x * Z0.y, 0.0f);
    }
    bar_lds();

    // ---- inverse DIT FFT: bit-reversed -> natural ----
    dit16_x(z, t);
    dit_wave16(z, wave, lane);
    dit_wave128(z, wave, lane);
    bar_lds();                     // last round reads cross-chunk
    float re[16];
    float mv = -3.0e38f;
    dit_last(z, t, re, mv);        // corr values stay in registers
    bar_lds();                     // z becomes argmax scratch

    // ---- LATE PREFETCH of next row: issued here so the loads' HBM/L3 latency
    //      hides under argmax + candidate scan + output stores. bar_lds never
    //      drains vmcnt, so they stay in flight until next-row staging uses
    //      them (compiler emits the counted vmcnt wait at first use).
    if (r + 1 < rmax) {
      const float4* x4 = (const float4*)(x + (size_t)(row + 1) * NFFT);
      const float4* r4 = (const float4*)(xref + (size_t)(row + 1) * NFFT);
      #pragma unroll
      for (int gi = 0; gi < 4; ++gi) { int q = t + TPB*gi; sx[gi] = x4[q]; sr[gi] = r4[q]; }
    }

    // ---- argmax: wave max -> block max -> candidate scan in registers ----
    float* zf = (float*)z;
    int*  zi = (int*)z;
    if (t == 0) zi[8] = 0;
    #pragma unroll
    for (int off = 32; off > 0; off >>= 1)
      mv = fmaxf(mv, __shfl_down(mv, off));
    if (lane == 0) zf[wave] = mv;
    bar_lds();
    float M = zf[0];
    #pragma unroll
    for (int w = 1; w < 8; ++w) M = fmaxf(M, zf[w]);
    // margin 4.0 corr units = 32768 raw (>>100x f32 FFT error bound).
    float thresh = M - 32768.0f;
    #pragma unroll
    for (int gi = 0; gi < 2; ++gi)
      #pragma unroll
      for (int k = 0; k < 8; ++k) {
        if (re[8*gi + k] >= thresh) {
          int pos = t + TPB*gi + 1024*k;
          int slot = atomicAdd(&zi[8], 1);
          if (slot < 40) zi[16 + slot] = pos;
        }
      }
    bar_lds();
    int count = zi[8];
    if (count > 40) count = 40;

    int bestPos;
    if (count == 1) {
      bestPos = zi[16];
    } else {
      // fp64 exact dot per candidate (np reference FFT is float64)
      double* zd = (double*)z;
      double bestV = -1.0e300;
      int bp = NFFT;
      for (int c = 0; c < count; ++c) {
        int pos = zi[16 + c];
        double part = 0.0;
        #pragma unroll 4
        for (int gi = 0; gi < VPT; ++gi) {
          int n = t + TPB*gi;
          part += (double)xrow[n] * (double)rrow[(n + pos) & (NFFT-1)];
        }
        #pragma unroll
        for (int off = 32; off > 0; off >>= 1)
          part += __shfl_down(part, off);
        if (lane == 0) zd[32 + wave] = part;
        bar_lds();
        if (t == 0) {
          double tot = 0.0;
          #pragma unroll
          for (int w = 0; w < 8; ++w) tot += zd[32 + w];
          if (tot > bestV || (tot == bestV && pos < bp)) { bestV = tot; bp = pos; }
        }
        bar_lds();
      }
      if (t == 0) zi[9] = bp;
      bar_lds();
      bestPos = zi[9];
    }

    // ---- outputs: x_aligned[k] = x[(k - ind) mod N]; inds as float.
    //      Stores are fire-and-forget: bar_lds never drains vmcnt.
    float* orow = out0 + (size_t)row * NFFT;
    #pragma unroll 4
    for (int gi = 0; gi < VPT; ++gi) {
      int kk = t + TPB*gi;
      orow[kk] = xrow[(kk - bestPos) & (NFFT-1)];
    }
    if (t == 0) outInd[row] = (float)bestPos;
  }
}

extern "C" void kernel_launch(void* const* d_in, const int* in_sizes, int n_in,
                              void* d_out, int out_size, void* d_ws, size_t ws_size,
                              hipStream_t stream) {
  const float* x    = (const float*)d_in[0];
  const float* xref = (const float*)d_in[1];
  float* out = (float*)d_out;
  const int rows = in_sizes[0] / NFFT;   // 32*64 = 2048
  float* outInd = out + (size_t)rows * NFFT;
  const int grid = (rows + ROWS - 1) / ROWS;   // 512 blocks = 2/CU resident
  hipLaunchKernelGGL(corr_align_kernel, dim3(grid), dim3(TPB), 0, stream,
                     x, xref, out, outInd, rows);
}

// Round 4
// 377.240 us; speedup vs baseline: 1.1171x; 1.1171x over previous
//
#include <hip/hip_runtime.h>
#include <hip/hip_bf16.h>

#define NFFT 8192
#define TPB  512
#define VPT  16   // NFFT / TPB
#define ROWS 4    // rows per block: 2048/4 = 512 blocks = exactly 2 resident/CU

// Native 2-wide float vector => compiler emits v_pk_add_f32 / v_pk_fma_f32.
typedef float f2 __attribute__((ext_vector_type(2)));

__device__ __forceinline__ f2 mk(float a, float b){ f2 r; r.x=a; r.y=b; return r; }
__device__ __forceinline__ f2 cswap(f2 a){ return __builtin_shufflevector(a,a,1,0); }

// Raw barrier: lgkmcnt(0)+s_barrier in ONE opaque asm. Unlike __syncthreads()
// this does NOT drain vmcnt, so output stores / staging loads stay in flight
// across barriers. Correctness proven R1-R3 (passed, absmax 0).
// NOTE (R1-R3 lesson): NO register-resident prefetch arrays anywhere — a 32-VGPR
// cross-phase live range pushes the kernel from 80 to 128 VGPRs and generates
// ~400 MB of scratch spill traffic (320 us). Staging must consume loads
// immediately (load -> ds_write), as in the proven round-0 structure.
__device__ __forceinline__ void bar_lds() {
  asm volatile("s_waitcnt lgkmcnt(0)\n\ts_barrier" ::: "memory");
}

// XOR swizzle at f2 granularity (physical layout identical to R4/R5).
// Rounds below use closed-form identities so swz costs 0-2 VALU per access:
//   swz(p + 1024k) = swz(p) + 1024k
//   swz(b + 128k)  = (swz(b) ^ 8(k&1)) + 128k
//   swz(b + 16k)   = (b&~15) + 16k + ((b&15) ^ 8(blk&1) ^ k)
//   swz(16t + c)   = 16t + (c ^ (t&15))
__device__ __forceinline__ int swz(int j) { return j ^ ((j >> 4) & 15); }
__device__ __forceinline__ int rev13(unsigned x) { return (int)(__brev(x) >> 19); }

// d * (c - i s)  (forward twiddle)
__device__ __forceinline__ f2 cmul_conj(f2 d, float c, float s){
  return d*c + cswap(d)*mk(s,-s);
}
// v * (c + i s)  (inverse twiddle)
__device__ __forceinline__ f2 cmul_pos(f2 v, float c, float s){
  return v*c + cswap(v)*mk(-s,s);
}

// ---- radix-8 butterfly cores; hw sin/cos in revolutions (verified R2-R5) ----
__device__ __forceinline__ void dif8_core(f2* y, int p_num, float inv_den) {
  float cA[4], sA[4], cB[2], sB[2], c4, s4;
  {
    float r = (float)p_num * inv_den;
    float sa = __builtin_amdgcn_sinf(r);
    float ca = __builtin_amdgcn_cosf(r);
    float c2 = ca*ca - sa*sa, s2 = 2.0f*ca*sa;
    c4 = c2*c2 - s2*s2; s4 = 2.0f*c2*s2;
    const float R = 0.70710678118654752f;
    cA[0] = ca;          sA[0] = sa;
    cA[1] = R*(ca-sa);   sA[1] = R*(ca+sa);
    cA[2] = -sa;         sA[2] = ca;
    cA[3] = -R*(ca+sa);  sA[3] = R*(ca-sa);
    cB[0] = c2;  sB[0] = s2;
    cB[1] = -s2; sB[1] = c2;
  }
  #pragma unroll
  for (int k = 0; k < 4; ++k) {
    f2 u = y[k], v = y[k+4];
    y[k] = u + v;
    y[k+4] = cmul_conj(u - v, cA[k], sA[k]);
  }
  #pragma unroll
  for (int h = 0; h < 8; h += 4)
    #pragma unroll
    for (int k0 = 0; k0 < 2; ++k0) {
      f2 u = y[h+k0], v = y[h+k0+2];
      y[h+k0] = u + v;
      y[h+k0+2] = cmul_conj(u - v, cB[k0], sB[k0]);
    }
  #pragma unroll
  for (int h = 0; h < 8; h += 2) {
    f2 u = y[h], v = y[h+1];
    y[h] = u + v;
    y[h+1] = cmul_conj(u - v, c4, s4);
  }
}

__device__ __forceinline__ void dit8_core(f2* y, int p_num, float inv_den) {
  float cA[4], sA[4], cB[2], sB[2], c4, s4;
  {
    float r = (float)p_num * inv_den;
    float sa = __builtin_amdgcn_sinf(r);
    float ca = __builtin_amdgcn_cosf(r);
    float c2 = ca*ca - sa*sa, s2 = 2.0f*ca*sa;
    c4 = c2*c2 - s2*s2; s4 = 2.0f*c2*s2;
    const float R = 0.70710678118654752f;
    cA[0] = ca;          sA[0] = sa;
    cA[1] = R*(ca-sa);   sA[1] = R*(ca+sa);
    cA[2] = -sa;         sA[2] = ca;
    cA[3] = -R*(ca+sa);  sA[3] = R*(ca-sa);
    cB[0] = c2;  sB[0] = s2;
    cB[1] = -s2; sB[1] = c2;
  }
  #pragma unroll
  for (int h = 0; h < 8; h += 2) {
    f2 u = y[h];
    f2 w = cmul_pos(y[h+1], c4, s4);
    y[h] = u + w; y[h+1] = u - w;
  }
  #pragma unroll
  for (int h = 0; h < 8; h += 4)
    #pragma unroll
    for (int k0 = 0; k0 < 2; ++k0) {
      f2 u = y[h+k0];
      f2 w = cmul_pos(y[h+k0+2], cB[k0], sB[k0]);
      y[h+k0] = u + w; y[h+k0+2] = u - w;
    }
  #pragma unroll
  for (int k = 0; k < 4; ++k) {
    f2 u = y[k];
    f2 w = cmul_pos(y[k+4], cA[k], sA[k]);
    y[k] = u + w; y[k+4] = u - w;
  }
}

// ---- GLOBAL forward round S=1024: swz(p+1024k) = swz(p)+1024k -> imm offsets
__device__ __forceinline__ void dif_global1024(f2* z, int t) {
  #pragma unroll
  for (int gi = 0; gi < 2; ++gi) {
    int p = t + TPB*gi;
    f2* B = z + swz(p);
    f2 y[8];
    #pragma unroll
    for (int k = 0; k < 8; ++k) y[k] = B[1024*k];
    dif8_core(y, p, 0.125f/1024.0f);
    #pragma unroll
    for (int k = 0; k < 8; ++k) B[1024*k] = y[k];
  }
  bar_lds();
}

// ---- WAVE-LOCAL S=128: two bases (swz(b), swz(b)^8) + imm offsets.
// No fence: a wave's DS ops retire in order (lgkmcnt in-order for LDS),
// so own-wave read-after-write across rounds is safe and pipelines.
__device__ __forceinline__ void dif_wave128(f2* z, int w, int l) {
  #pragma unroll
  for (int gi = 0; gi < 2; ++gi) {
    int gl = l + 64*gi;
    int E = swz(w*1024 + gl);
    f2* B0 = z + E;
    f2* B1 = z + (E ^ 8);
    f2 y[8];
    #pragma unroll
    for (int k = 0; k < 8; ++k) y[k] = (k&1) ? B1[128*k] : B0[128*k];
    dif8_core(y, gl, 0.125f/128.0f);
    #pragma unroll
    for (int k = 0; k < 8; ++k) { if (k&1) B1[128*k] = y[k]; else B0[128*k] = y[k]; }
  }
}

__device__ __forceinline__ void dit_wave128(f2* z, int w, int l) {
  #pragma unroll
  for (int gi = 0; gi < 2; ++gi) {
    int gl = l + 64*gi;
    int E = swz(w*1024 + gl);
    f2* B0 = z + E;
    f2* B1 = z + (E ^ 8);
    f2 y[8];
    #pragma unroll
    for (int k = 0; k < 8; ++k) y[k] = (k&1) ? B1[128*k] : B0[128*k];
    dit8_core(y, gl, 0.125f/128.0f);
    #pragma unroll
    for (int k = 0; k < 8; ++k) { if (k&1) B1[128*k] = y[k]; else B0[128*k] = y[k]; }
  }
}

// ---- WAVE-LOCAL S=16: swz(b+16k) = H + 16k + (e^k), e = p ^ 8(blk&1)
__device__ __forceinline__ void dif_wave16(f2* z, int w, int l) {
  #pragma unroll
  for (int gi = 0; gi < 2; ++gi) {
    int gl = l + 64*gi;
    int p = gl & 15, blk = gl >> 4;
    int e = p ^ (8*(blk&1));
    f2* H = z + (w*1024 + blk*128);
    f2 y[8];
    #pragma unroll
    for (int k = 0; k < 8; ++k) y[k] = H[16*k + (e ^ k)];
    dif8_core(y, p, 0.125f/16.0f);
    #pragma unroll
    for (int k = 0; k < 8; ++k) H[16*k + (e ^ k)] = y[k];
  }
}

__device__ __forceinline__ void dit_wave16(f2* z, int w, int l) {
  #pragma unroll
  for (int gi = 0; gi < 2; ++gi) {
    int gl = l + 64*gi;
    int p = gl & 15, blk = gl >> 4;
    int e = p ^ (8*(blk&1));
    f2* H = z + (w*1024 + blk*128);
    f2 y[8];
    #pragma unroll
    for (int k = 0; k < 8; ++k) y[k] = H[16*k + (e ^ k)];
    dit8_core(y, p, 0.125f/16.0f);
    #pragma unroll
    for (int k = 0; k < 8; ++k) H[16*k + (e ^ k)] = y[k];
  }
}

#define C16_1 0.92387953251128674f
#define S16_1 0.38268343236508978f
#define RSQ2  0.70710678118654752f

// ---- radix-16 const-twiddle rounds: swz(16t+c) = 16t + (c ^ (t&15))
__device__ __forceinline__ void dif16_x(f2* z, int t) {
  const float C8[8] = {1.f, C16_1, RSQ2, S16_1, 0.f, -S16_1, -RSQ2, -C16_1};
  const float S8[8] = {0.f, S16_1, RSQ2, C16_1, 1.f,  C16_1,  RSQ2,  S16_1};
  int e = t & 15;
  f2* H = z + 16*t;
  f2 y[16];
  #pragma unroll
  for (int c = 0; c < 16; ++c) y[c] = H[c ^ e];
  #pragma unroll
  for (int j = 0; j < 8; ++j) {
    f2 u = y[j], v = y[j+8];
    y[j] = u + v;
    y[j+8] = cmul_conj(u - v, C8[j], S8[j]);
  }
  #pragma unroll
  for (int h = 0; h < 16; h += 8)
    #pragma unroll
    for (int j = 0; j < 4; ++j) {
      f2 u = y[h+j], v = y[h+j+4];
      y[h+j] = u + v;
      y[h+j+4] = cmul_conj(u - v, C8[2*j], S8[2*j]);
    }
  #pragma unroll
  for (int h = 0; h < 16; h += 4)
    #pragma unroll
    for (int j = 0; j < 2; ++j) {
      f2 u = y[h+j], v = y[h+j+2];
      y[h+j] = u + v;
      f2 d = u - v;
      y[h+j+2] = j ? mk(d.y, -d.x) : d;
    }
  #pragma unroll
  for (int h = 0; h < 16; h += 2) {
    f2 u = y[h], v = y[h+1];
    y[h] = u + v; y[h+1] = u - v;
  }
  #pragma unroll
  for (int c = 0; c < 16; ++c) H[c ^ e] = y[c];
}

__device__ __forceinline__ void dit16_x(f2* z, int t) {
  const float C8[8] = {1.f, C16_1, RSQ2, S16_1, 0.f, -S16_1, -RSQ2, -C16_1};
  const float S8[8] = {0.f, S16_1, RSQ2, C16_1, 1.f,  C16_1,  RSQ2,  S16_1};
  int e = t & 15;
  f2* H = z + 16*t;
  f2 y[16];
  #pragma unroll
  for (int c = 0; c < 16; ++c) y[c] = H[c ^ e];
  #pragma unroll
  for (int h = 0; h < 16; h += 2) {
    f2 u = y[h], v = y[h+1];
    y[h] = u + v; y[h+1] = u - v;
  }
  #pragma unroll
  for (int h = 0; h < 16; h += 4)
    #pragma unroll
    for (int j = 0; j < 2; ++j) {
      f2 u = y[h+j];
      f2 v = y[h+j+2];
      f2 w = j ? mk(-v.y, v.x) : v;
      y[h+j] = u + w; y[h+j+2] = u - w;
    }
  #pragma unroll
  for (int h = 0; h < 16; h += 8)
    #pragma unroll
    for (int j = 0; j < 4; ++j) {
      f2 u = y[h+j];
      f2 w = cmul_pos(y[h+j+4], C8[2*j], S8[2*j]);
      y[h+j] = u + w; y[h+j+4] = u - w;
    }
  #pragma unroll
  for (int j = 0; j < 8; ++j) {
    f2 u = y[j];
    f2 w = cmul_pos(y[j+8], C8[j], S8[j]);
    y[j] = u + w; y[j+8] = u - w;
  }
  #pragma unroll
  for (int c = 0; c < 16; ++c) H[c ^ e] = y[c];
}

// Last inverse round (global S=1024): imm offsets; results stay in registers.
__device__ __forceinline__ void dit_last(const f2* z, int t, float* re, float& mv) {
  #pragma unroll
  for (int gi = 0; gi < 2; ++gi) {
    int g = t + TPB*gi;
    const f2* B = z + swz(g);
    f2 y[8];
    #pragma unroll
    for (int k = 0; k < 8; ++k) y[k] = B[1024*k];
    dit8_core(y, g, 0.125f/1024.0f);
    #pragma unroll
    for (int k = 0; k < 8; ++k) {
      re[8*gi + k] = y[k].x;     // corr*N at position g + 1024*k
      mv = fmaxf(mv, y[k].x);
    }
  }
}

// NO waves-per-EU constraint (R1: min-occupancy bound => 64-VGPR target =>
// ~1.1 GB spill, 470 us). Plain bound gave VGPR=80 spill-free in round-0.
__global__ __launch_bounds__(TPB)
void corr_align_kernel(const float* __restrict__ x, const float* __restrict__ xref,
                       float* __restrict__ out0, float* __restrict__ outInd,
                       int nrows) {
  __shared__ f2 z[NFFT];   // 64 KiB
  const int t = threadIdx.x;
  const int lane = t & 63, wave = t >> 6;
  const int row0 = blockIdx.x * ROWS;
  const int rmax = (nrows - row0 < ROWS) ? (nrows - row0) : ROWS;

  for (int r = 0; r < rmax; ++r) {
    const int row = row0 + r;
    const float* xrow = x + (size_t)row * NFFT;
    const float* rrow = xref + (size_t)row * NFFT;

    // z was argmax scratch for the previous row: all readers must be done.
    bar_lds();

    // ---- stage: z[n] = x[n] + i*xref[n], round-0 style: load -> ds_write
    //      immediately, no register-resident arrays. Previous row's output
    //      stores are still in flight here (bar_lds never drains vmcnt).
    {
      const float4* x4 = (const float4*)xrow;
      const float4* r4 = (const float4*)rrow;
      #pragma unroll
      for (int gi = 0; gi < 4; ++gi) {
        int q = t + TPB*gi;
        float4 xv = x4[q], rv = r4[q];
        int j = 4*q;
        z[swz(j+0)] = mk(xv.x, rv.x);
        z[swz(j+1)] = mk(xv.y, rv.y);
        z[swz(j+2)] = mk(xv.z, rv.z);
        z[swz(j+3)] = mk(xv.w, rv.w);
      }
    }
    bar_lds();

    // ---- forward DIF FFT: natural -> bit-reversed ----
    dif_global1024(z, t);          // cross-wave, bar_lds inside
    dif_wave128(z, wave, lane);    // wave-local: own-chunk, DS-order safe
    dif_wave16(z, wave, lane);
    dif16_x(z, t);
    bar_lds();                     // unpack reads cross-chunk

    // ---- unpack + cross-spectrum, PAIR-OWNED ----
    #pragma unroll
    for (int gi = 0; gi < 8; ++gi) {
      int k = 8*t + gi + 1;                       // 1..4096
      int p = rev13((unsigned)k);
      int q = rev13((unsigned)((NFFT - k) & (NFFT-1)));
      f2 Zp = z[swz(p)];
      f2 Zq = z[swz(q)];
      float Xx = 0.5f*(Zp.x + Zq.x);
      float Xy = 0.5f*(Zp.y - Zq.y);
      float Yx = 0.5f*(Zp.y + Zq.y);
      float Yy = 0.5f*(Zq.x - Zp.x);
      f2 Gk = mk(Xx*Yx + Xy*Yy, Xx*Yy - Xy*Yx);
      z[swz(p)] = Gk;
      if (k != NFFT/2) z[swz(q)] = mk(Gk.x, -Gk.y);
    }
    if (t == 0) {
      f2 Z0 = z[0];
      z[0] = mk(Z0.x * Z0.y, 0.0f);
    }
    bar_lds();

    // ---- inverse DIT FFT: bit-reversed -> natural ----
    dit16_x(z, t);
    dit_wave16(z, wave, lane);
    dit_wave128(z, wave, lane);
    bar_lds();                     // last round reads cross-chunk
    float re[16];
    float mv = -3.0e38f;
    dit_last(z, t, re, mv);        // corr values stay in registers
    bar_lds();                     // z becomes argmax scratch

    // ---- argmax: wave max -> block max -> candidate scan in registers ----
    float* zf = (float*)z;
    int*  zi = (int*)z;
    if (t == 0) zi[8] = 0;
    #pragma unroll
    for (int off = 32; off > 0; off >>= 1)
      mv = fmaxf(mv, __shfl_down(mv, off));
    if (lane == 0) zf[wave] = mv;
    bar_lds();
    float M = zf[0];
    #pragma unroll
    for (int w = 1; w < 8; ++w) M = fmaxf(M, zf[w]);
    // margin 4.0 corr units = 32768 raw (>>100x f32 FFT error bound).
    float thresh = M - 32768.0f;
    #pragma unroll
    for (int gi = 0; gi < 2; ++gi)
      #pragma unroll
      for (int k = 0; k < 8; ++k) {
        if (re[8*gi + k] >= thresh) {
          int pos = t + TPB*gi + 1024*k;
          int slot = atomicAdd(&zi[8], 1);
          if (slot < 40) zi[16 + slot] = pos;
        }
      }
    bar_lds();
    int count = zi[8];
    if (count > 40) count = 40;

    int bestPos;
    if (count == 1) {
      bestPos = zi[16];
    } else {
      // fp64 exact dot per candidate (np reference FFT is float64)
      double* zd = (double*)z;
      double bestV = -1.0e300;
      int bp = NFFT;
      for (int c = 0; c < count; ++c) {
        int pos = zi[16 + c];
        double part = 0.0;
        #pragma unroll 4
        for (int gi = 0; gi < VPT; ++gi) {
          int n = t + TPB*gi;
          part += (double)xrow[n] * (double)rrow[(n + pos) & (NFFT-1)];
        }
        #pragma unroll
        for (int off = 32; off > 0; off >>= 1)
          part += __shfl_down(part, off);
        if (lane == 0) zd[32 + wave] = part;
        bar_lds();
        if (t == 0) {
          double tot = 0.0;
          #pragma unroll
          for (int w = 0; w < 8; ++w) tot += zd[32 + w];
          if (tot > bestV || (tot == bestV && pos < bp)) { bestV = tot; bp = pos; }
        }
        bar_lds();
      }
      if (t == 0) zi[9] = bp;
      bar_lds();
      bestPos = zi[9];
    }

    // ---- outputs: x_aligned[k] = x[(k - ind) mod N]; inds as float.
    //      Stores are fire-and-forget: next row's bar_lds never drains vmcnt,
    //      so these overlap the next row's staging loads + forward FFT.
    float* orow = out0 + (size_t)row * NFFT;
    #pragma unroll 4
    for (int gi = 0; gi < VPT; ++gi) {
      int kk = t + TPB*gi;
      orow[kk] = xrow[(kk - bestPos) & (NFFT-1)];
    }
    if (t == 0) outInd[row] = (float)bestPos;
  }
}

extern "C" void kernel_launch(void* const* d_in, const int* in_sizes, int n_in,
                              void* d_out, int out_size, void* d_ws, size_t ws_size,
                              hipStream_t stream) {
  const float* x    = (const float*)d_in[0];
  const float* xref = (const float*)d_in[1];
  float* out = (float*)d_out;
  const int rows = in_sizes[0] / NFFT;   // 32*64 = 2048
  float* outInd = out + (size_t)rows * NFFT;
  const int grid = (rows + ROWS - 1) / ROWS;   // 512 blocks = 2/CU resident
  hipLaunchKernelGGL(corr_align_kernel, dim3(grid), dim3(TPB), 0, stream,
                     x, xref, out, outInd, rows);
}

// Round 5
// 344.565 us; speedup vs baseline: 1.2230x; 1.0948x over previous
//
#include <hip/hip_runtime.h>
#include <hip/hip_bf16.h>

#define NFFT 8192
#define TPB  1024
#define VPT  8    // NFFT / TPB

// Native 2-wide float vector => compiler emits v_pk_add_f32 / v_pk_fma_f32.
typedef float f2 __attribute__((ext_vector_type(2)));

__device__ __forceinline__ f2 mk(float a, float b){ f2 r; r.x=a; r.y=b; return r; }
__device__ __forceinline__ f2 cswap(f2 a){ return __builtin_shufflevector(a,a,1,0); }

// Raw barrier: lgkmcnt(0)+s_barrier, no vmcnt drain (proven correct R1-R4).
// LESSONS (R1-R4): (1) never set a waves/EU bound on a VPT=16 body (64-VGPR
// target => ~1 GB spill); (2) no register arrays live across phases; (3) the
// multi-row in-block loop spills ~20 regs/row regardless of prefetch — dead axis.
// This version instead doubles TLP: TPB=1024/VPT=8 halves per-thread state so
// the body genuinely fits 64 VGPR => 2 blocks x 16 waves = 32 waves/CU (HW max).
__device__ __forceinline__ void bar_lds() {
  asm volatile("s_waitcnt lgkmcnt(0)\n\ts_barrier" ::: "memory");
}

// XOR swizzle at f2 granularity. Closed-form identities (verified):
//   swz(p + 1024k) = swz(p) + 1024k
//   swz(b + 128k)  = (swz(b) ^ 8(k&1)) + 128k      [b = seg*1024 + gl, gl<128]
//   swz(b + 16k)   = base + 16k + (e ^ k), e = p ^ 8(blk&1)
//   swz(16t + c)   = 16t + (c ^ (t&15))
__device__ __forceinline__ int swz(int j) { return j ^ ((j >> 4) & 15); }
__device__ __forceinline__ int rev13(unsigned x) { return (int)(__brev(x) >> 19); }

// d * (c - i s)  (forward twiddle)
__device__ __forceinline__ f2 cmul_conj(f2 d, float c, float s){
  return d*c + cswap(d)*mk(s,-s);
}
// v * (c + i s)  (inverse twiddle)
__device__ __forceinline__ f2 cmul_pos(f2 v, float c, float s){
  return v*c + cswap(v)*mk(-s,s);
}

// ---- radix-8 butterfly cores; hw sin/cos in revolutions (verified) ----
__device__ __forceinline__ void dif8_core(f2* y, int p_num, float inv_den) {
  float cA[4], sA[4], cB[2], sB[2], c4, s4;
  {
    float r = (float)p_num * inv_den;
    float sa = __builtin_amdgcn_sinf(r);
    float ca = __builtin_amdgcn_cosf(r);
    float c2 = ca*ca - sa*sa, s2 = 2.0f*ca*sa;
    c4 = c2*c2 - s2*s2; s4 = 2.0f*c2*s2;
    const float R = 0.70710678118654752f;
    cA[0] = ca;          sA[0] = sa;
    cA[1] = R*(ca-sa);   sA[1] = R*(ca+sa);
    cA[2] = -sa;         sA[2] = ca;
    cA[3] = -R*(ca+sa);  sA[3] = R*(ca-sa);
    cB[0] = c2;  sB[0] = s2;
    cB[1] = -s2; sB[1] = c2;
  }
  #pragma unroll
  for (int k = 0; k < 4; ++k) {
    f2 u = y[k], v = y[k+4];
    y[k] = u + v;
    y[k+4] = cmul_conj(u - v, cA[k], sA[k]);
  }
  #pragma unroll
  for (int h = 0; h < 8; h += 4)
    #pragma unroll
    for (int k0 = 0; k0 < 2; ++k0) {
      f2 u = y[h+k0], v = y[h+k0+2];
      y[h+k0] = u + v;
      y[h+k0+2] = cmul_conj(u - v, cB[k0], sB[k0]);
    }
  #pragma unroll
  for (int h = 0; h < 8; h += 2) {
    f2 u = y[h], v = y[h+1];
    y[h] = u + v;
    y[h+1] = cmul_conj(u - v, c4, s4);
  }
}

__device__ __forceinline__ void dit8_core(f2* y, int p_num, float inv_den) {
  float cA[4], sA[4], cB[2], sB[2], c4, s4;
  {
    float r = (float)p_num * inv_den;
    float sa = __builtin_amdgcn_sinf(r);
    float ca = __builtin_amdgcn_cosf(r);
    float c2 = ca*ca - sa*sa, s2 = 2.0f*ca*sa;
    c4 = c2*c2 - s2*s2; s4 = 2.0f*c2*s2;
    const float R = 0.70710678118654752f;
    cA[0] = ca;          sA[0] = sa;
    cA[1] = R*(ca-sa);   sA[1] = R*(ca+sa);
    cA[2] = -sa;         sA[2] = ca;
    cA[3] = -R*(ca+sa);  sA[3] = R*(ca-sa);
    cB[0] = c2;  sB[0] = s2;
    cB[1] = -s2; sB[1] = c2;
  }
  #pragma unroll
  for (int h = 0; h < 8; h += 2) {
    f2 u = y[h];
    f2 w = cmul_pos(y[h+1], c4, s4);
    y[h] = u + w; y[h+1] = u - w;
  }
  #pragma unroll
  for (int h = 0; h < 8; h += 4)
    #pragma unroll
    for (int k0 = 0; k0 < 2; ++k0) {
      f2 u = y[h+k0];
      f2 w = cmul_pos(y[h+k0+2], cB[k0], sB[k0]);
      y[h+k0] = u + w; y[h+k0+2] = u - w;
    }
  #pragma unroll
  for (int k = 0; k < 4; ++k) {
    f2 u = y[k];
    f2 w = cmul_pos(y[k+4], cA[k], sA[k]);
    y[k] = u + w; y[k+4] = u - w;
  }
}

// ---- round 1 (fwd): radix-8, stride 1024; one butterfly per thread ----
__device__ __forceinline__ void dif_s1024(f2* z, int t) {
  f2* B = z + swz(t);
  f2 y[8];
  #pragma unroll
  for (int k = 0; k < 8; ++k) y[k] = B[1024*k];
  dif8_core(y, t, 0.125f/1024.0f);
  #pragma unroll
  for (int k = 0; k < 8; ++k) B[1024*k] = y[k];
}

// ---- stride-128 round: thread t -> segment t>>7, butterfly t&127 ----
__device__ __forceinline__ void dif_s128(f2* z, int t) {
  int gl = t & 127, seg = t >> 7;
  int E = swz(seg*1024 + gl);
  f2* B0 = z + E;
  f2* B1 = z + (E ^ 8);
  f2 y[8];
  #pragma unroll
  for (int k = 0; k < 8; ++k) y[k] = (k&1) ? B1[128*k] : B0[128*k];
  dif8_core(y, gl, 0.125f/128.0f);
  #pragma unroll
  for (int k = 0; k < 8; ++k) { if (k&1) B1[128*k] = y[k]; else B0[128*k] = y[k]; }
}

__device__ __forceinline__ void dit_s128(f2* z, int t) {
  int gl = t & 127, seg = t >> 7;
  int E = swz(seg*1024 + gl);
  f2* B0 = z + E;
  f2* B1 = z + (E ^ 8);
  f2 y[8];
  #pragma unroll
  for (int k = 0; k < 8; ++k) y[k] = (k&1) ? B1[128*k] : B0[128*k];
  dit8_core(y, gl, 0.125f/128.0f);
  #pragma unroll
  for (int k = 0; k < 8; ++k) { if (k&1) B1[128*k] = y[k]; else B0[128*k] = y[k]; }
}

// ---- stride-16 round: swz(base+16k+p) = base + 16k + (e^k) ----
__device__ __forceinline__ void dif_s16(f2* z, int t) {
  int gl = t & 127, seg = t >> 7;
  int p = gl & 15, blk = gl >> 4;
  int e = p ^ (8*(blk&1));
  f2* H = z + (seg*1024 + blk*128);
  f2 y[8];
  #pragma unroll
  for (int k = 0; k < 8; ++k) y[k] = H[16*k + (e ^ k)];
  dif8_core(y, p, 0.125f/16.0f);
  #pragma unroll
  for (int k = 0; k < 8; ++k) H[16*k + (e ^ k)] = y[k];
}

__device__ __forceinline__ void dit_s16(f2* z, int t) {
  int gl = t & 127, seg = t >> 7;
  int p = gl & 15, blk = gl >> 4;
  int e = p ^ (8*(blk&1));
  f2* H = z + (seg*1024 + blk*128);
  f2 y[8];
  #pragma unroll
  for (int k = 0; k < 8; ++k) y[k] = H[16*k + (e ^ k)];
  dit8_core(y, p, 0.125f/16.0f);
  #pragma unroll
  for (int k = 0; k < 8; ++k) H[16*k + (e ^ k)] = y[k];
}

#define C16_1 0.92387953251128674f
#define S16_1 0.38268343236508978f
#define RSQ2  0.70710678118654752f

// ---- radix-16 const-twiddle round (512 butterflies -> threads t<512) ----
__device__ __forceinline__ void dif16_x(f2* z, int t) {
  const float C8[8] = {1.f, C16_1, RSQ2, S16_1, 0.f, -S16_1, -RSQ2, -C16_1};
  const float S8[8] = {0.f, S16_1, RSQ2, C16_1, 1.f,  C16_1,  RSQ2,  S16_1};
  int e = t & 15;
  f2* H = z + 16*t;
  f2 y[16];
  #pragma unroll
  for (int c = 0; c < 16; ++c) y[c] = H[c ^ e];
  #pragma unroll
  for (int j = 0; j < 8; ++j) {
    f2 u = y[j], v = y[j+8];
    y[j] = u + v;
    y[j+8] = cmul_conj(u - v, C8[j], S8[j]);
  }
  #pragma unroll
  for (int h = 0; h < 16; h += 8)
    #pragma unroll
    for (int j = 0; j < 4; ++j) {
      f2 u = y[h+j], v = y[h+j+4];
      y[h+j] = u + v;
      y[h+j+4] = cmul_conj(u - v, C8[2*j], S8[2*j]);
    }
  #pragma unroll
  for (int h = 0; h < 16; h += 4)
    #pragma unroll
    for (int j = 0; j < 2; ++j) {
      f2 u = y[h+j], v = y[h+j+2];
      y[h+j] = u + v;
      f2 d = u - v;
      y[h+j+2] = j ? mk(d.y, -d.x) : d;
    }
  #pragma unroll
  for (int h = 0; h < 16; h += 2) {
    f2 u = y[h], v = y[h+1];
    y[h] = u + v; y[h+1] = u - v;
  }
  #pragma unroll
  for (int c = 0; c < 16; ++c) H[c ^ e] = y[c];
}

__device__ __forceinline__ void dit16_x(f2* z, int t) {
  const float C8[8] = {1.f, C16_1, RSQ2, S16_1, 0.f, -S16_1, -RSQ2, -C16_1};
  const float S8[8] = {0.f, S16_1, RSQ2, C16_1, 1.f,  C16_1,  RSQ2,  S16_1};
  int e = t & 15;
  f2* H = z + 16*t;
  f2 y[16];
  #pragma unroll
  for (int c = 0; c < 16; ++c) y[c] = H[c ^ e];
  #pragma unroll
  for (int h = 0; h < 16; h += 2) {
    f2 u = y[h], v = y[h+1];
    y[h] = u + v; y[h+1] = u - v;
  }
  #pragma unroll
  for (int h = 0; h < 16; h += 4)
    #pragma unroll
    for (int j = 0; j < 2; ++j) {
      f2 u = y[h+j];
      f2 v = y[h+j+2];
      f2 w = j ? mk(-v.y, v.x) : v;
      y[h+j] = u + w; y[h+j+2] = u - w;
    }
  #pragma unroll
  for (int h = 0; h < 16; h += 8)
    #pragma unroll
    for (int j = 0; j < 4; ++j) {
      f2 u = y[h+j];
      f2 w = cmul_pos(y[h+j+4], C8[2*j], S8[2*j]);
      y[h+j] = u + w; y[h+j+4] = u - w;
    }
  #pragma unroll
  for (int j = 0; j < 8; ++j) {
    f2 u = y[j];
    f2 w = cmul_pos(y[j+8], C8[j], S8[j]);
    y[j] = u + w; y[j+8] = u - w;
  }
  #pragma unroll
  for (int c = 0; c < 16; ++c) H[c ^ e] = y[c];
}

// Last inverse round (stride 1024): results stay in registers.
__device__ __forceinline__ void dit_last(const f2* z, int t, float* re, float& mv) {
  const f2* B = z + swz(t);
  f2 y[8];
  #pragma unroll
  for (int k = 0; k < 8; ++k) y[k] = B[1024*k];
  dit8_core(y, t, 0.125f/1024.0f);
  #pragma unroll
  for (int k = 0; k < 8; ++k) {
    re[k] = y[k].x;              // corr*N at position t + 1024*k
    mv = fmaxf(mv, y[k].x);
  }
}

// __launch_bounds__(1024, 8): 8 waves/EU => k = 8*4/(1024/64) = 2 blocks/CU
// => 32 waves/CU (HW max). Targets 64 VGPR; VPT=8 body estimated ~50 peak.
// THE GATE: if FETCH/WRITE inflate past ~66 MB, this spilled — revert.
__global__ __launch_bounds__(TPB, 8)
void corr_align_kernel(const float* __restrict__ x, const float* __restrict__ xref,
                       float* __restrict__ out0, float* __restrict__ outInd) {
  __shared__ f2 z[NFFT];   // 64 KiB
  const int t = threadIdx.x;
  const int lane = t & 63, wave = t >> 6;   // 16 waves
  const int row = blockIdx.x;
  const float* xrow = x + (size_t)row * NFFT;
  const float* rrow = xref + (size_t)row * NFFT;

  // ---- stage: z[n] = x[n] + i*xref[n]; load -> ds_write immediately ----
  {
    const float4* x4 = (const float4*)xrow;
    const float4* r4 = (const float4*)rrow;
    #pragma unroll
    for (int gi = 0; gi < 2; ++gi) {
      int q = t + TPB*gi;
      float4 xv = x4[q], rv = r4[q];
      int j = 4*q;
      z[swz(j+0)] = mk(xv.x, rv.x);
      z[swz(j+1)] = mk(xv.y, rv.y);
      z[swz(j+2)] = mk(xv.z, rv.z);
      z[swz(j+3)] = mk(xv.w, rv.w);
    }
  }
  bar_lds();

  // ---- forward DIF FFT: natural -> bit-reversed ----
  // With 16 waves, segments are shared by wave pairs: every round handoff is
  // cross-wave => barrier between ALL rounds (unlike the 8-wave version).
  dif_s1024(z, t);
  bar_lds();
  dif_s128(z, t);
  bar_lds();
  dif_s16(z, t);
  bar_lds();
  if (t < 512) dif16_x(z, t);
  bar_lds();

  // ---- unpack + cross-spectrum, PAIR-OWNED (k = 4t+gi+1 in 1..4096) ----
  #pragma unroll
  for (int gi = 0; gi < 4; ++gi) {
    int k = 4*t + gi + 1;
    int p = rev13((unsigned)k);
    int q = rev13((unsigned)((NFFT - k) & (NFFT-1)));
    f2 Zp = z[swz(p)];
    f2 Zq = z[swz(q)];
    float Xx = 0.5f*(Zp.x + Zq.x);
    float Xy = 0.5f*(Zp.y - Zq.y);
    float Yx = 0.5f*(Zp.y + Zq.y);
    float Yy = 0.5f*(Zq.x - Zp.x);
    f2 Gk = mk(Xx*Yx + Xy*Yy, Xx*Yy - Xy*Yx);
    z[swz(p)] = Gk;
    if (k != NFFT/2) z[swz(q)] = mk(Gk.x, -Gk.y);
  }
  if (t == 0) {
    f2 Z0 = z[0];
    z[0] = mk(Z0.x * Z0.y, 0.0f);
  }
  bar_lds();

  // ---- inverse DIT FFT: bit-reversed -> natural ----
  if (t < 512) dit16_x(z, t);
  bar_lds();
  dit_s16(z, t);
  bar_lds();
  dit_s128(z, t);
  bar_lds();
  float re[VPT];
  float mv = -3.0e38f;
  dit_last(z, t, re, mv);          // corr values stay in registers
  bar_lds();                       // z becomes argmax scratch

  // ---- argmax: wave max -> block max -> candidate scan ----
  // LDS scratch layout (bytes): zf[0..15]=0..63 wave maxima; zi[16]=64 count;
  // zi[17]=68 bestPos; zi[18..57]=72..231 candidates; zd[32..47]=256..383 dots.
  float* zf = (float*)z;
  int*  zi = (int*)z;
  if (t == 0) zi[16] = 0;
  #pragma unroll
  for (int off = 32; off > 0; off >>= 1)
    mv = fmaxf(mv, __shfl_down(mv, off));
  if (lane == 0) zf[wave] = mv;
  bar_lds();
  float M = zf[0];
  #pragma unroll
  for (int w = 1; w < 16; ++w) M = fmaxf(M, zf[w]);
  // margin 4.0 corr units = 32768 raw (>>100x f32 FFT error bound).
  float thresh = M - 32768.0f;
  #pragma unroll
  for (int k = 0; k < VPT; ++k) {
    if (re[k] >= thresh) {
      int pos = t + 1024*k;
      int slot = atomicAdd(&zi[16], 1);
      if (slot < 40) zi[18 + slot] = pos;
    }
  }
  bar_lds();
  int count = zi[16];
  if (count > 40) count = 40;

  int bestPos;
  if (count == 1) {
    bestPos = zi[18];
  } else {
    // fp64 exact dot per candidate (np reference FFT is float64)
    double* zd = (double*)z;
    double bestV = -1.0e300;
    int bp = NFFT;
    for (int c = 0; c < count; ++c) {
      int pos = zi[18 + c];
      double part = 0.0;
      #pragma unroll 4
      for (int gi = 0; gi < VPT; ++gi) {
        int n = t + TPB*gi;
        part += (double)xrow[n] * (double)rrow[(n + pos) & (NFFT-1)];
      }
      #pragma unroll
      for (int off = 32; off > 0; off >>= 1)
        part += __shfl_down(part, off);
      if (lane == 0) zd[32 + wave] = part;
      bar_lds();
      if (t == 0) {
        double tot = 0.0;
        #pragma unroll
        for (int w = 0; w < 16; ++w) tot += zd[32 + w];
        if (tot > bestV || (tot == bestV && pos < bp)) { bestV = tot; bp = pos; }
      }
      bar_lds();
    }
    if (t == 0) zi[17] = bp;
    bar_lds();
    bestPos = zi[17];
  }

  // ---- outputs: x_aligned[k] = x[(k - ind) mod N]; inds as float ----
  float* orow = out0 + (size_t)row * NFFT;
  #pragma unroll 4
  for (int gi = 0; gi < VPT; ++gi) {
    int kk = t + TPB*gi;
    orow[kk] = xrow[(kk - bestPos) & (NFFT-1)];
  }
  if (t == 0) outInd[row] = (float)bestPos;
}

extern "C" void kernel_launch(void* const* d_in, const int* in_sizes, int n_in,
                              void* d_out, int out_size, void* d_ws, size_t ws_size,
                              hipStream_t stream) {
  const float* x    = (const float*)d_in[0];
  const float* xref = (const float*)d_in[1];
  float* out = (float*)d_out;
  const int rows = in_sizes[0] / NFFT;   // 32*64 = 2048
  float* outInd = out + (size_t)rows * NFFT;
  hipLaunchKernelGGL(corr_align_kernel, dim3(rows), dim3(TPB), 0, stream,
                     x, xref, out, outInd);
}

// Round 6
// 239.164 us; speedup vs baseline: 1.7620x; 1.4407x over previous
//
#include <hip/hip_runtime.h>
#include <hip/hip_bf16.h>

#define NFFT 8192
#define TPB  1024
#define VPT  8    // NFFT / TPB

// Native 2-wide float vector => compiler emits v_pk_add_f32 / v_pk_fma_f32.
typedef float f2 __attribute__((ext_vector_type(2)));

__device__ __forceinline__ f2 mk(float a, float b){ f2 r; r.x=a; r.y=b; return r; }
__device__ __forceinline__ f2 cswap(f2 a){ return __builtin_shufflevector(a,a,1,0); }

// Raw barrier: lgkmcnt(0)+s_barrier, no vmcnt drain (proven correct R1-R5).
//
// LAUNCH-BOUNDS CALIBRATION (R1/R5 evidence): on this toolchain the 2nd arg
// behaves as MIN WORKGROUPS PER CU (CUDA semantics), NOT waves/EU:
//   (512,4)  -> 4 blk x  8 waves = 32 waves/CU -> 64-VGPR target (observed 64)
//   (1024,8) -> 8 blk x 16 waves = capped      -> 32-VGPR target (observed 32)
// So (1024,2) -> 2 blk x 16 waves = 32 waves/CU (HW max) -> 64-VGPR target.
// The VPT=8 body peaks ~50-60 regs => fits 64 without spill (unlike the VPT=16
// body, which needs ~112 and spills catastrophically under any cap < 128).
__device__ __forceinline__ void bar_lds() {
  asm volatile("s_waitcnt lgkmcnt(0)\n\ts_barrier" ::: "memory");
}

// XOR swizzle at f2 granularity. Closed-form identities (verified):
//   swz(p + 1024k) = swz(p) + 1024k
//   swz(b + 128k)  = (swz(b) ^ 8(k&1)) + 128k      [b = seg*1024 + gl, gl<128]
//   swz(b + 16k)   = base + 16k + (e ^ k), e = p ^ 8(blk&1)
//   swz(16t + c)   = 16t + (c ^ (t&15))
__device__ __forceinline__ int swz(int j) { return j ^ ((j >> 4) & 15); }
__device__ __forceinline__ int rev13(unsigned x) { return (int)(__brev(x) >> 19); }

// d * (c - i s)  (forward twiddle)
__device__ __forceinline__ f2 cmul_conj(f2 d, float c, float s){
  return d*c + cswap(d)*mk(s,-s);
}
// v * (c + i s)  (inverse twiddle)
__device__ __forceinline__ f2 cmul_pos(f2 v, float c, float s){
  return v*c + cswap(v)*mk(-s,s);
}

// ---- radix-8 butterfly cores; hw sin/cos in revolutions (verified) ----
__device__ __forceinline__ void dif8_core(f2* y, int p_num, float inv_den) {
  float cA[4], sA[4], cB[2], sB[2], c4, s4;
  {
    float r = (float)p_num * inv_den;
    float sa = __builtin_amdgcn_sinf(r);
    float ca = __builtin_amdgcn_cosf(r);
    float c2 = ca*ca - sa*sa, s2 = 2.0f*ca*sa;
    c4 = c2*c2 - s2*s2; s4 = 2.0f*c2*s2;
    const float R = 0.70710678118654752f;
    cA[0] = ca;          sA[0] = sa;
    cA[1] = R*(ca-sa);   sA[1] = R*(ca+sa);
    cA[2] = -sa;         sA[2] = ca;
    cA[3] = -R*(ca+sa);  sA[3] = R*(ca-sa);
    cB[0] = c2;  sB[0] = s2;
    cB[1] = -s2; sB[1] = c2;
  }
  #pragma unroll
  for (int k = 0; k < 4; ++k) {
    f2 u = y[k], v = y[k+4];
    y[k] = u + v;
    y[k+4] = cmul_conj(u - v, cA[k], sA[k]);
  }
  #pragma unroll
  for (int h = 0; h < 8; h += 4)
    #pragma unroll
    for (int k0 = 0; k0 < 2; ++k0) {
      f2 u = y[h+k0], v = y[h+k0+2];
      y[h+k0] = u + v;
      y[h+k0+2] = cmul_conj(u - v, cB[k0], sB[k0]);
    }
  #pragma unroll
  for (int h = 0; h < 8; h += 2) {
    f2 u = y[h], v = y[h+1];
    y[h] = u + v;
    y[h+1] = cmul_conj(u - v, c4, s4);
  }
}

__device__ __forceinline__ void dit8_core(f2* y, int p_num, float inv_den) {
  float cA[4], sA[4], cB[2], sB[2], c4, s4;
  {
    float r = (float)p_num * inv_den;
    float sa = __builtin_amdgcn_sinf(r);
    float ca = __builtin_amdgcn_cosf(r);
    float c2 = ca*ca - sa*sa, s2 = 2.0f*ca*sa;
    c4 = c2*c2 - s2*s2; s4 = 2.0f*c2*s2;
    const float R = 0.70710678118654752f;
    cA[0] = ca;          sA[0] = sa;
    cA[1] = R*(ca-sa);   sA[1] = R*(ca+sa);
    cA[2] = -sa;         sA[2] = ca;
    cA[3] = -R*(ca+sa);  sA[3] = R*(ca-sa);
    cB[0] = c2;  sB[0] = s2;
    cB[1] = -s2; sB[1] = c2;
  }
  #pragma unroll
  for (int h = 0; h < 8; h += 2) {
    f2 u = y[h];
    f2 w = cmul_pos(y[h+1], c4, s4);
    y[h] = u + w; y[h+1] = u - w;
  }
  #pragma unroll
  for (int h = 0; h < 8; h += 4)
    #pragma unroll
    for (int k0 = 0; k0 < 2; ++k0) {
      f2 u = y[h+k0];
      f2 w = cmul_pos(y[h+k0+2], cB[k0], sB[k0]);
      y[h+k0] = u + w; y[h+k0+2] = u - w;
    }
  #pragma unroll
  for (int k = 0; k < 4; ++k) {
    f2 u = y[k];
    f2 w = cmul_pos(y[k+4], cA[k], sA[k]);
    y[k] = u + w; y[k+4] = u - w;
  }
}

// ---- round 1 (fwd): radix-8, stride 1024; one butterfly per thread ----
__device__ __forceinline__ void dif_s1024(f2* z, int t) {
  f2* B = z + swz(t);
  f2 y[8];
  #pragma unroll
  for (int k = 0; k < 8; ++k) y[k] = B[1024*k];
  dif8_core(y, t, 0.125f/1024.0f);
  #pragma unroll
  for (int k = 0; k < 8; ++k) B[1024*k] = y[k];
}

// ---- stride-128 round: thread t -> segment t>>7, butterfly t&127 ----
__device__ __forceinline__ void dif_s128(f2* z, int t) {
  int gl = t & 127, seg = t >> 7;
  int E = swz(seg*1024 + gl);
  f2* B0 = z + E;
  f2* B1 = z + (E ^ 8);
  f2 y[8];
  #pragma unroll
  for (int k = 0; k < 8; ++k) y[k] = (k&1) ? B1[128*k] : B0[128*k];
  dif8_core(y, gl, 0.125f/128.0f);
  #pragma unroll
  for (int k = 0; k < 8; ++k) { if (k&1) B1[128*k] = y[k]; else B0[128*k] = y[k]; }
}

__device__ __forceinline__ void dit_s128(f2* z, int t) {
  int gl = t & 127, seg = t >> 7;
  int E = swz(seg*1024 + gl);
  f2* B0 = z + E;
  f2* B1 = z + (E ^ 8);
  f2 y[8];
  #pragma unroll
  for (int k = 0; k < 8; ++k) y[k] = (k&1) ? B1[128*k] : B0[128*k];
  dit8_core(y, gl, 0.125f/128.0f);
  #pragma unroll
  for (int k = 0; k < 8; ++k) { if (k&1) B1[128*k] = y[k]; else B0[128*k] = y[k]; }
}

// ---- stride-16 round: swz(base+16k+p) = base + 16k + (e^k) ----
__device__ __forceinline__ void dif_s16(f2* z, int t) {
  int gl = t & 127, seg = t >> 7;
  int p = gl & 15, blk = gl >> 4;
  int e = p ^ (8*(blk&1));
  f2* H = z + (seg*1024 + blk*128);
  f2 y[8];
  #pragma unroll
  for (int k = 0; k < 8; ++k) y[k] = H[16*k + (e ^ k)];
  dif8_core(y, p, 0.125f/16.0f);
  #pragma unroll
  for (int k = 0; k < 8; ++k) H[16*k + (e ^ k)] = y[k];
}

__device__ __forceinline__ void dit_s16(f2* z, int t) {
  int gl = t & 127, seg = t >> 7;
  int p = gl & 15, blk = gl >> 4;
  int e = p ^ (8*(blk&1));
  f2* H = z + (seg*1024 + blk*128);
  f2 y[8];
  #pragma unroll
  for (int k = 0; k < 8; ++k) y[k] = H[16*k + (e ^ k)];
  dit8_core(y, p, 0.125f/16.0f);
  #pragma unroll
  for (int k = 0; k < 8; ++k) H[16*k + (e ^ k)] = y[k];
}

#define C16_1 0.92387953251128674f
#define S16_1 0.38268343236508978f
#define RSQ2  0.70710678118654752f

// ---- radix-16 const-twiddle round (512 butterflies -> threads t<512) ----
__device__ __forceinline__ void dif16_x(f2* z, int t) {
  const float C8[8] = {1.f, C16_1, RSQ2, S16_1, 0.f, -S16_1, -RSQ2, -C16_1};
  const float S8[8] = {0.f, S16_1, RSQ2, C16_1, 1.f,  C16_1,  RSQ2,  S16_1};
  int e = t & 15;
  f2* H = z + 16*t;
  f2 y[16];
  #pragma unroll
  for (int c = 0; c < 16; ++c) y[c] = H[c ^ e];
  #pragma unroll
  for (int j = 0; j < 8; ++j) {
    f2 u = y[j], v = y[j+8];
    y[j] = u + v;
    y[j+8] = cmul_conj(u - v, C8[j], S8[j]);
  }
  #pragma unroll
  for (int h = 0; h < 16; h += 8)
    #pragma unroll
    for (int j = 0; j < 4; ++j) {
      f2 u = y[h+j], v = y[h+j+4];
      y[h+j] = u + v;
      y[h+j+4] = cmul_conj(u - v, C8[2*j], S8[2*j]);
    }
  #pragma unroll
  for (int h = 0; h < 16; h += 4)
    #pragma unroll
    for (int j = 0; j < 2; ++j) {
      f2 u = y[h+j], v = y[h+j+2];
      y[h+j] = u + v;
      f2 d = u - v;
      y[h+j+2] = j ? mk(d.y, -d.x) : d;
    }
  #pragma unroll
  for (int h = 0; h < 16; h += 2) {
    f2 u = y[h], v = y[h+1];
    y[h] = u + v; y[h+1] = u - v;
  }
  #pragma unroll
  for (int c = 0; c < 16; ++c) H[c ^ e] = y[c];
}

__device__ __forceinline__ void dit16_x(f2* z, int t) {
  const float C8[8] = {1.f, C16_1, RSQ2, S16_1, 0.f, -S16_1, -RSQ2, -C16_1};
  const float S8[8] = {0.f, S16_1, RSQ2, C16_1, 1.f,  C16_1,  RSQ2,  S16_1};
  int e = t & 15;
  f2* H = z + 16*t;
  f2 y[16];
  #pragma unroll
  for (int c = 0; c < 16; ++c) y[c] = H[c ^ e];
  #pragma unroll
  for (int h = 0; h < 16; h += 2) {
    f2 u = y[h], v = y[h+1];
    y[h] = u + v; y[h+1] = u - v;
  }
  #pragma unroll
  for (int h = 0; h < 16; h += 4)
    #pragma unroll
    for (int j = 0; j < 2; ++j) {
      f2 u = y[h+j];
      f2 v = y[h+j+2];
      f2 w = j ? mk(-v.y, v.x) : v;
      y[h+j] = u + w; y[h+j+2] = u - w;
    }
  #pragma unroll
  for (int h = 0; h < 16; h += 8)
    #pragma unroll
    for (int j = 0; j < 4; ++j) {
      f2 u = y[h+j];
      f2 w = cmul_pos(y[h+j+4], C8[2*j], S8[2*j]);
      y[h+j] = u + w; y[h+j+4] = u - w;
    }
  #pragma unroll
  for (int j = 0; j < 8; ++j) {
    f2 u = y[j];
    f2 w = cmul_pos(y[j+8], C8[j], S8[j]);
    y[j] = u + w; y[j+8] = u - w;
  }
  #pragma unroll
  for (int c = 0; c < 16; ++c) H[c ^ e] = y[c];
}

// Last inverse round (stride 1024): results stay in registers.
__device__ __forceinline__ void dit_last(const f2* z, int t, float* re, float& mv) {
  const f2* B = z + swz(t);
  f2 y[8];
  #pragma unroll
  for (int k = 0; k < 8; ++k) y[k] = B[1024*k];
  dit8_core(y, t, 0.125f/1024.0f);
  #pragma unroll
  for (int k = 0; k < 8; ++k) {
    re[k] = y[k].x;              // corr*N at position t + 1024*k
    mv = fmaxf(mv, y[k].x);
  }
}

// (1024, 2): 2 workgroups/CU (see calibration note above) = 32 waves/CU
// (HW max), 64-VGPR target. GATE: FETCH/WRITE must stay ~66 MB each.
__global__ __launch_bounds__(TPB, 2)
void corr_align_kernel(const float* __restrict__ x, const float* __restrict__ xref,
                       float* __restrict__ out0, float* __restrict__ outInd) {
  __shared__ f2 z[NFFT];   // 64 KiB
  const int t = threadIdx.x;
  const int lane = t & 63, wave = t >> 6;   // 16 waves
  const int row = blockIdx.x;
  const float* xrow = x + (size_t)row * NFFT;
  const float* rrow = xref + (size_t)row * NFFT;

  // ---- stage: z[n] = x[n] + i*xref[n]; load -> ds_write immediately ----
  {
    const float4* x4 = (const float4*)xrow;
    const float4* r4 = (const float4*)rrow;
    #pragma unroll
    for (int gi = 0; gi < 2; ++gi) {
      int q = t + TPB*gi;
      float4 xv = x4[q], rv = r4[q];
      int j = 4*q;
      z[swz(j+0)] = mk(xv.x, rv.x);
      z[swz(j+1)] = mk(xv.y, rv.y);
      z[swz(j+2)] = mk(xv.z, rv.z);
      z[swz(j+3)] = mk(xv.w, rv.w);
    }
  }
  bar_lds();

  // ---- forward DIF FFT: natural -> bit-reversed ----
  // With 16 waves, segments are shared by wave pairs: every round handoff is
  // cross-wave => barrier between ALL rounds.
  dif_s1024(z, t);
  bar_lds();
  dif_s128(z, t);
  bar_lds();
  dif_s16(z, t);
  bar_lds();
  if (t < 512) dif16_x(z, t);
  bar_lds();

  // ---- unpack + cross-spectrum, PAIR-OWNED (k = 4t+gi+1 in 1..4096) ----
  #pragma unroll
  for (int gi = 0; gi < 4; ++gi) {
    int k = 4*t + gi + 1;
    int p = rev13((unsigned)k);
    int q = rev13((unsigned)((NFFT - k) & (NFFT-1)));
    f2 Zp = z[swz(p)];
    f2 Zq = z[swz(q)];
    float Xx = 0.5f*(Zp.x + Zq.x);
    float Xy = 0.5f*(Zp.y - Zq.y);
    float Yx = 0.5f*(Zp.y + Zq.y);
    float Yy = 0.5f*(Zq.x - Zp.x);
    f2 Gk = mk(Xx*Yx + Xy*Yy, Xx*Yy - Xy*Yx);
    z[swz(p)] = Gk;
    if (k != NFFT/2) z[swz(q)] = mk(Gk.x, -Gk.y);
  }
  if (t == 0) {
    f2 Z0 = z[0];
    z[0] = mk(Z0.x * Z0.y, 0.0f);
  }
  bar_lds();

  // ---- inverse DIT FFT: bit-reversed -> natural ----
  if (t < 512) dit16_x(z, t);
  bar_lds();
  dit_s16(z, t);
  bar_lds();
  dit_s128(z, t);
  bar_lds();
  float re[VPT];
  float mv = -3.0e38f;
  dit_last(z, t, re, mv);          // corr values stay in registers
  bar_lds();                       // z becomes argmax scratch

  // ---- argmax: wave max -> block max -> candidate scan ----
  // LDS scratch layout (words): zf[0..15] wave maxima; zi[16] count;
  // zi[17] bestPos; zi[18..57] candidates; zd[32..47] per-wave dots.
  float* zf = (float*)z;
  int*  zi = (int*)z;
  if (t == 0) zi[16] = 0;
  #pragma unroll
  for (int off = 32; off > 0; off >>= 1)
    mv = fmaxf(mv, __shfl_down(mv, off));
  if (lane == 0) zf[wave] = mv;
  bar_lds();
  float M = zf[0];
  #pragma unroll
  for (int w = 1; w < 16; ++w) M = fmaxf(M, zf[w]);
  // margin 4.0 corr units = 32768 raw (>>100x f32 FFT error bound).
  float thresh = M - 32768.0f;
  #pragma unroll
  for (int k = 0; k < VPT; ++k) {
    if (re[k] >= thresh) {
      int pos = t + 1024*k;
      int slot = atomicAdd(&zi[16], 1);
      if (slot < 40) zi[18 + slot] = pos;
    }
  }
  bar_lds();
  int count = zi[16];
  if (count > 40) count = 40;

  int bestPos;
  if (count == 1) {
    bestPos = zi[18];
  } else {
    // fp64 exact dot per candidate (np reference FFT is float64)
    double* zd = (double*)z;
    double bestV = -1.0e300;
    int bp = NFFT;
    for (int c = 0; c < count; ++c) {
      int pos = zi[18 + c];
      double part = 0.0;
      #pragma unroll 2
      for (int gi = 0; gi < VPT; ++gi) {
        int n = t + TPB*gi;
        part += (double)xrow[n] * (double)rrow[(n + pos) & (NFFT-1)];
      }
      #pragma unroll
      for (int off = 32; off > 0; off >>= 1)
        part += __shfl_down(part, off);
      if (lane == 0) zd[32 + wave] = part;
      bar_lds();
      if (t == 0) {
        double tot = 0.0;
        #pragma unroll
        for (int w = 0; w < 16; ++w) tot += zd[32 + w];
        if (tot > bestV || (tot == bestV && pos < bp)) { bestV = tot; bp = pos; }
      }
      bar_lds();
    }
    if (t == 0) zi[17] = bp;
    bar_lds();
    bestPos = zi[17];
  }

  // ---- outputs: x_aligned[k] = x[(k - ind) mod N]; inds as float ----
  float* orow = out0 + (size_t)row * NFFT;
  #pragma unroll 2
  for (int gi = 0; gi < VPT; ++gi) {
    int kk = t + TPB*gi;
    orow[kk] = xrow[(kk - bestPos) & (NFFT-1)];
  }
  if (t == 0) outInd[row] = (float)bestPos;
}

extern "C" void kernel_launch(void* const* d_in, const int* in_sizes, int n_in,
                              void* d_out, int out_size, void* d_ws, size_t ws_size,
                              hipStream_t stream) {
  const float* x    = (const float*)d_in[0];
  const float* xref = (const float*)d_in[1];
  float* out = (float*)d_out;
  const int rows = in_sizes[0] / NFFT;   // 32*64 = 2048
  float* outInd = out + (size_t)rows * NFFT;
  hipLaunchKernelGGL(corr_align_kernel, dim3(rows), dim3(TPB), 0, stream,
                     x, xref, out, outInd);
}